// Round 5
// baseline (2223.322 us; speedup 1.0000x reference)
//
#include <hip/hip_runtime.h>
#include <math.h>
#include <stdint.h>

// ---------------------------------------------------------------------------
// SNN forward — R5: scalar-scan sparse recurrence + LDS-tiled layer-1 GEMM.
//
// Bit-exactness contract (established R3/R4, absmax 4.88e-4):
//   - layer-1: per (b,t,h): c=0; for d ascending: c=fmaf(w,x,c); then
//     __fadd_rn(c, bias). (product commutes exactly; order preserved here)
//   - spike layers: sum over spiking k ASCENDING of W[k-row], sequential
//     __fadd_rn chain seeded 0 (== fmaf(1,w,c) path of the dense reference;
//     skipped k adds exactly 0). Sentinel k=256 hits a zeroed row: c+0=c.
//   - LIF: individually-rounded fp32 ops, reset from PREVIOUS mem.
//
// R4 post-mortem: 45% VALUBusy at 21% occupancy; VALU dominated by address
// math + idx LDS reads + list building; 6 barriers/timestep. R5: one row per
// block (1024 blocks, 4/CU), ballot words shared via LDS once per layer
// (3 barriers/timestep, double-buffered), readfirstlane -> SGPR masks,
// uniform scalar ctz walk, loads off scalar bases (k uniform). ~2 VALU per
// spike per row.
// ---------------------------------------------------------------------------

namespace {

constexpr int Bsz = 1024;
constexpr int Dd  = 256;
constexpr int Tt  = 128;
constexpr int Hh  = 256;
constexpr int Oo  = 64;

// Wt[c*R + r] = W[r*C + c] for c<C; row c==C zeroed (sparse sentinel target).
__global__ void pack_t(const float* __restrict__ W, float* __restrict__ Wt,
                       int R, int C) {
    int idx = blockIdx.x * 256 + threadIdx.x;
    if (idx >= (C + 1) * R) return;
    int c = idx / R, r = idx - c * R;
    Wt[idx] = (c < C) ? W[(size_t)r * C + c] : 0.f;
}

__device__ __forceinline__ float clamp01(float v) { return fminf(fmaxf(v, 0.f), 1.f); }

__device__ __forceinline__ bool lif_step(float& m, float cur, float B, float Th) {
    const float r = (__fsub_rn(m, Th) > 0.f) ? Th : 0.f;   // reset from PREVIOUS mem
    m = __fsub_rn(__fadd_rn(__fmul_rn(B, m), cur), r);
    return __fsub_rn(m, Th) > 0.f;
}

// Extract next set-bit index (ascending); sentinel Hh (zero row) when empty.
__device__ __forceinline__ int nextk(uint64_t& m, int kb) {
    const int k = (m == 0) ? Hh : ((int)__builtin_ctzll(m) + kb);
    m &= m - 1;                       // m==0 stays 0
    return k;
}

// Sum of tab[k*STRIDE + off] over spiking k ascending; 4 loads in flight.
template<int STRIDE>
__device__ __forceinline__ float sparse_sum(const uint64_t* mw,
                                            const float* __restrict__ tab, int off) {
    float c = 0.f;
    #pragma unroll
    for (int wI = 0; wI < 4; ++wI) {
        uint64_t m = mw[wI];
        const int kb = wI * 64;
        while (m) {
            const int k0 = nextk(m, kb);
            const int k1 = nextk(m, kb);
            const int k2 = nextk(m, kb);
            const int k3 = nextk(m, kb);
            // k uniform (from SGPR masks) -> scalar base + vector offset
            const float v0 = tab[(size_t)k0 * STRIDE + off];
            const float v1 = tab[(size_t)k1 * STRIDE + off];
            const float v2 = tab[(size_t)k2 * STRIDE + off];
            const float v3 = tab[(size_t)k3 * STRIDE + off];
            c = __fadd_rn(c, v0);
            c = __fadd_rn(c, v1);
            c = __fadd_rn(c, v2);
            c = __fadd_rn(c, v3);
        }
    }
    return c;
}

// Ballot own wave, share 4 words via LDS (double-buffered, ONE barrier),
// readfirstlane into uniform SGPR masks.
__device__ __forceinline__ void share_masks(bool p, int tid,
                                            uint64_t (*mbuf)[4], int pb,
                                            uint64_t* mw) {
    const uint64_t bm = __ballot(p);
    if ((tid & 63) == 0) mbuf[pb][tid >> 6] = bm;
    __syncthreads();
    #pragma unroll
    for (int i = 0; i < 4; ++i) {
        const uint64_t v = mbuf[pb][i];
        const uint32_t lo = __builtin_amdgcn_readfirstlane((uint32_t)v);
        const uint32_t hi = __builtin_amdgcn_readfirstlane((uint32_t)(v >> 32));
        mw[i] = ((uint64_t)hi << 32) | lo;
    }
}

// ---------------- recurrent kernel: one batch row per block ----------------
__global__ __launch_bounds__(256) void snn_rec(
    const float* __restrict__ cur1,     // [b][t_local][h]
    const float* __restrict__ Wt_h, const float* __restrict__ Wt_h1,
    const float* __restrict__ Wt_f, const float* __restrict__ Wt_a,
    const float* __restrict__ beta1, const float* __restrict__ thr1,
    const float* __restrict__ b_h,  const float* __restrict__ beta2, const float* __restrict__ thr2,
    const float* __restrict__ b_h1,
    const float* __restrict__ b_f,  const float* __restrict__ beta_f,
    const float* __restrict__ b_a,  const float* __restrict__ beta_a,
    float* __restrict__ m1s, float* __restrict__ m2s, float* __restrict__ m3s,
    float* __restrict__ mos, float* __restrict__ out,
    int TC, int first)
{
    __shared__ uint64_t mbuf[2][4];

    const int tid = threadIdx.x;
    const int h   = tid;
    const int b   = blockIdx.x;

    const float B1  = clamp01(beta1[h]), Th1 = thr1[h];
    const float bh  = b_h[h];
    const float B2  = clamp01(beta2[h]), Th2 = thr2[h];
    const float bh1 = b_h1[h];
    const int o   = h & 63;
    const int sel = (h >> 6) & 1;                 // wave-uniform mf/ma select
    const float bo = sel ? b_a[o] : b_f[o];
    const float Bo = clamp01(sel ? beta_a[o] : beta_f[o]);
    const float* __restrict__ tabO = sel ? Wt_a : Wt_f;

    float m1, m2, m3, mo;
    if (first) { m1 = m2 = m3 = mo = 0.f; }
    else {
        m1 = m1s[(size_t)b * Hh + h];
        m2 = m2s[(size_t)b * Hh + h];
        m3 = m3s[(size_t)b * Hh + h];
        mo = (h < 128) ? mos[(size_t)b * 128 + h] : 0.f;
    }

    const float* __restrict__ curb = cur1 + (size_t)b * TC * Hh;
    int pb = 0;
    uint64_t mw[4];

    float cnext = curb[h];                        // prefetch t=0
    for (int t = 0; t < TC; ++t) {
        bool p = lif_step(m1, cnext, B1, Th1);
        share_masks(p, tid, mbuf, pb, mw); pb ^= 1;
        if (t + 1 < TC) cnext = curb[(t + 1) * Hh + h];   // prefetch next t

        p = lif_step(m2, __fadd_rn(sparse_sum<Hh>(mw, Wt_h, h), bh), B2, Th2);
        share_masks(p, tid, mbuf, pb, mw); pb ^= 1;

        p = lif_step(m3, __fadd_rn(sparse_sum<Hh>(mw, Wt_h1, h), bh1), B2, Th2);  // layer-3 reuses beta2/thr2
        share_masks(p, tid, mbuf, pb, mw); pb ^= 1;

        if (h < 128)
            mo = __fadd_rn(__fmul_rn(Bo, mo), __fadd_rn(sparse_sum<Oo>(mw, tabO, o), bo));
    }

    m1s[(size_t)b * Hh + h] = m1;
    m2s[(size_t)b * Hh + h] = m2;
    m3s[(size_t)b * Hh + h] = m3;
    if (h < 128) {
        mos[(size_t)b * 128 + h] = mo;
        float* dst = out + (sel ? (size_t)Bsz * Oo : 0);
        dst[(size_t)b * Oo + o] = (float)(1.0 / (1.0 + exp(-(double)mo)));
    }
}

// ---------------- layer-1 GEMM, LDS-tiled (TT = chunk width, >=8) ----------
template<int TT>
__global__ __launch_bounds__(256) void gemm_l1_lds(
    const float* __restrict__ x, const float* __restrict__ Wt_in,
    const float* __restrict__ b_in, float* __restrict__ cur1, int tg0)
{
    __shared__ float xs[Dd][TT];      // TT=32 -> 32 KiB
    const int h = threadIdx.x;
    const int b = blockIdx.x;
    const float* xb = x + (size_t)b * Dd * Tt + tg0;
    constexpr int T4 = TT / 4;
    for (int v = threadIdx.x; v < Dd * T4; v += 256) {
        const int d = v / T4, j4 = v - d * T4;
        const float4 val = *(const float4*)(xb + (size_t)d * Tt + j4 * 4);
        *(float4*)&xs[d][j4 * 4] = val;
    }
    __syncthreads();
    float c[TT];
    #pragma unroll
    for (int j = 0; j < TT; ++j) c[j] = 0.f;
    for (int d = 0; d < Dd; ++d) {
        const float w = Wt_in[d * Hh + h];        // coalesced 1KB/wave-group
        #pragma unroll
        for (int j = 0; j < TT; ++j) c[j] = fmaf(w, xs[d][j], c[j]);  // broadcast LDS
    }
    const float bb = b_in[h];
    float* cb = cur1 + (size_t)b * TT * Hh;       // [b][t_local][h]
    #pragma unroll
    for (int j = 0; j < TT; ++j) cb[j * Hh + h] = __fadd_rn(c[j], bb);
}

// fallback for tiny chunks (TT < 8): direct uniform x reads
template<int TT>
__global__ __launch_bounds__(256) void gemm_l1_simple(
    const float* __restrict__ x, const float* __restrict__ Wt_in,
    const float* __restrict__ b_in, float* __restrict__ cur1, int tg0)
{
    const int h = threadIdx.x;
    const int b = blockIdx.x;
    float c[TT];
    #pragma unroll
    for (int j = 0; j < TT; ++j) c[j] = 0.f;
    const float* xb = x + (size_t)b * Dd * Tt + tg0;
    for (int d = 0; d < Dd; ++d) {
        const float w = Wt_in[d * Hh + h];
        const float* xp = xb + (size_t)d * Tt;
        #pragma unroll
        for (int j = 0; j < TT; ++j) c[j] = fmaf(w, xp[j], c[j]);
    }
    const float bb = b_in[h];
    float* cb = cur1 + (size_t)b * TT * Hh;
    #pragma unroll
    for (int j = 0; j < TT; ++j) cb[j * Hh + h] = __fadd_rn(c[j], bb);
}

} // namespace

extern "C" void kernel_launch(void* const* d_in, const int* in_sizes, int n_in,
                              void* d_out, int out_size, void* d_ws, size_t ws_size,
                              hipStream_t stream) {
    const float* x      = (const float*)d_in[0];
    const float* W_in   = (const float*)d_in[1];
    const float* b_in   = (const float*)d_in[2];
    const float* beta1  = (const float*)d_in[3];
    const float* thr1   = (const float*)d_in[4];
    const float* W_h    = (const float*)d_in[5];
    const float* b_h    = (const float*)d_in[6];
    const float* beta2  = (const float*)d_in[7];
    const float* thr2   = (const float*)d_in[8];
    const float* W_h1   = (const float*)d_in[9];
    const float* b_h1   = (const float*)d_in[10];
    const float* W_f    = (const float*)d_in[11];
    const float* b_f    = (const float*)d_in[12];
    const float* beta_f = (const float*)d_in[13];
    const float* W_a    = (const float*)d_in[14];
    const float* b_a    = (const float*)d_in[15];
    const float* beta_a = (const float*)d_in[16];
    float* out = (float*)d_out;

    float* ws = (float*)d_ws;
    size_t off = 0;
    auto alloc = [&](size_t n) { float* p = ws + off; off += n; return p; };
    float* Wt_in = alloc(257 * 256);
    float* Wt_h  = alloc(257 * 256);
    float* Wt_h1 = alloc(257 * 256);
    float* Wt_f  = alloc(257 * 64);
    float* Wt_a  = alloc(257 * 64);
    float* m1s   = alloc((size_t)Bsz * Hh);
    float* m2s   = alloc((size_t)Bsz * Hh);
    float* m3s   = alloc((size_t)Bsz * Hh);
    float* mos   = alloc((size_t)Bsz * 128);
    const size_t fixed = off;

    int TC = 1;
    const int cands[6] = {32, 16, 8, 4, 2, 1};
    for (int i = 0; i < 6; ++i) {
        if ((fixed + (size_t)cands[i] * Bsz * Hh) * sizeof(float) <= ws_size) { TC = cands[i]; break; }
    }
    float* cur1 = alloc((size_t)TC * Bsz * Hh);

    pack_t<<<257, 256, 0, stream>>>(W_in, Wt_in, 256, 256);
    pack_t<<<257, 256, 0, stream>>>(W_h,  Wt_h,  256, 256);
    pack_t<<<257, 256, 0, stream>>>(W_h1, Wt_h1, 256, 256);
    pack_t<<<65,  256, 0, stream>>>(W_f,  Wt_f,  64, 256);
    pack_t<<<65,  256, 0, stream>>>(W_a,  Wt_a,  64, 256);

    const int nch = Tt / TC;
    for (int c = 0; c < nch; ++c) {
        const int tg = c * TC;
        if (TC == 32)      gemm_l1_lds<32><<<Bsz, 256, 0, stream>>>(x, Wt_in, b_in, cur1, tg);
        else if (TC == 16) gemm_l1_lds<16><<<Bsz, 256, 0, stream>>>(x, Wt_in, b_in, cur1, tg);
        else if (TC == 8)  gemm_l1_lds<8><<<Bsz, 256, 0, stream>>>(x, Wt_in, b_in, cur1, tg);
        else if (TC == 4)  gemm_l1_simple<4><<<Bsz, 256, 0, stream>>>(x, Wt_in, b_in, cur1, tg);
        else if (TC == 2)  gemm_l1_simple<2><<<Bsz, 256, 0, stream>>>(x, Wt_in, b_in, cur1, tg);
        else               gemm_l1_simple<1><<<Bsz, 256, 0, stream>>>(x, Wt_in, b_in, cur1, tg);

        snn_rec<<<Bsz, 256, 0, stream>>>(
            cur1, Wt_h, Wt_h1, Wt_f, Wt_a,
            beta1, thr1, b_h, beta2, thr2, b_h1,
            b_f, beta_f, b_a, beta_a,
            m1s, m2s, m3s, mos, out, TC, (c == 0) ? 1 : 0);
    }
}

// Round 6
// 1949.487 us; speedup vs baseline: 1.1405x; 1.1405x over previous
//
#include <hip/hip_runtime.h>
#include <math.h>
#include <stdint.h>

// ---------------------------------------------------------------------------
// SNN forward — R6: wave-per-row recurrence, float4 spike gathers, depth-2
// explicit load pipeline, zero barriers.
//
// Bit-exactness contract (R3..R5, absmax 4.882812e-4):
//   - layer-1: c=0; for d ascending: c=fmaf(w,x,c); then __fadd_rn(c,bias)
//   - spike layers: sum over spiking k ASCENDING, sequential __fadd_rn chain
//     seeded 0; sentinel k=256 hits zeroed row (c+0=c; c never -0)
//   - LIF: individually-rounded fp32 ops, reset from PREVIOUS mem
//
// R5 post-mortem: dynamic while(m) walk -> no load pipelining -> 465us/chunk,
// VALUBusy 20%. R6: lane owns 4 contiguous neurons (1 dwordx4 per spike
// feeds 4 fadds), spikes exchanged via shfl+ballot (no LDS, no barriers),
// 16 loads in flight via manual depth-2 pipeline.
// ---------------------------------------------------------------------------

namespace {

constexpr int Bsz = 1024;
constexpr int Dd  = 256;
constexpr int Tt  = 128;
constexpr int Hh  = 256;
constexpr int Oo  = 64;

// Wt[c*R + r] = W[r*C + c] for c<C; row c==C zeroed (sparse sentinel target).
__global__ void pack_t(const float* __restrict__ W, float* __restrict__ Wt,
                       int R, int C) {
    int idx = blockIdx.x * 256 + threadIdx.x;
    if (idx >= (C + 1) * R) return;
    int c = idx / R, r = idx - c * R;
    Wt[idx] = (c < C) ? W[(size_t)r * C + c] : 0.f;
}

// WtO[k*128 + o]: o<64 -> W_f[o][k], o>=64 -> W_a[o-64][k]; row k==256 zeroed.
__global__ void pack_o(const float* __restrict__ Wf, const float* __restrict__ Wa,
                       float* __restrict__ WtO) {
    int idx = blockIdx.x * 256 + threadIdx.x;
    if (idx >= 257 * 128) return;
    int k = idx >> 7, o = idx & 127;
    float v = 0.f;
    if (k < 256) v = (o < 64) ? Wf[(size_t)o * 256 + k] : Wa[(size_t)(o - 64) * 256 + k];
    WtO[idx] = v;
}

__device__ __forceinline__ float clamp01(float v) { return fminf(fmaxf(v, 0.f), 1.f); }

__device__ __forceinline__ bool lif_step(float& m, float cur, float B, float Th) {
    const float r = (__fsub_rn(m, Th) > 0.f) ? Th : 0.f;   // reset from PREVIOUS mem
    m = __fsub_rn(__fadd_rn(__fmul_rn(B, m), cur), r);
    return __fsub_rn(m, Th) > 0.f;
}

struct Masks { uint64_t m[4]; };

__device__ __forceinline__ bool any(const Masks& M) {
    return (M.m[0] | M.m[1] | M.m[2] | M.m[3]) != 0;
}

// Pop lowest set bit across the 256-bit mask (ascending neuron order);
// sentinel Hh when empty. Uniform (scalar) control flow.
__device__ __forceinline__ int nk1(Masks& M) {
    if (M.m[0]) { int k = __builtin_ctzll(M.m[0]);       M.m[0] &= M.m[0] - 1; return k; }
    if (M.m[1]) { int k = 64  + __builtin_ctzll(M.m[1]); M.m[1] &= M.m[1] - 1; return k; }
    if (M.m[2]) { int k = 128 + __builtin_ctzll(M.m[2]); M.m[2] &= M.m[2] - 1; return k; }
    if (M.m[3]) { int k = 192 + __builtin_ctzll(M.m[3]); M.m[3] &= M.m[3] - 1; return k; }
    return Hh;
}

__device__ __forceinline__ void ext8(Masks& M, int* k) {
    #pragma unroll
    for (int i = 0; i < 8; ++i) k[i] = nk1(M);
}

// Build masks from 4 spike bits/lane: mask q bit L = spike of neuron 64q+L,
// owned by lane 16q+(L>>2), bit (L&3).
__device__ __forceinline__ Masks make_masks(int nib, int lane) {
    Masks M;
    #pragma unroll
    for (int q = 0; q < 4; ++q) {
        const int v   = __shfl(nib, 16 * q + (lane >> 2), 64);
        const int bit = (v >> (lane & 3)) & 1;
        M.m[q] = __ballot(bit != 0);
    }
    return M;
}

__device__ __forceinline__ void load8h(float4* w, const float* __restrict__ tab,
                                       const int* k, int off4) {
    #pragma unroll
    for (int i = 0; i < 8; ++i)
        w[i] = *(const float4*)(tab + (size_t)k[i] * Hh + off4);
}

__device__ __forceinline__ void cons8h(float4& c, const float4* w) {
    #pragma unroll
    for (int i = 0; i < 8; ++i) {
        c.x = __fadd_rn(c.x, w[i].x);
        c.y = __fadd_rn(c.y, w[i].y);
        c.z = __fadd_rn(c.z, w[i].z);
        c.w = __fadd_rn(c.w, w[i].w);
    }
}

// Sum of W rows over spiking k ascending; depth-2 pipelined 8-load batches.
__device__ __forceinline__ float4 hid_sum(Masks M, const float* __restrict__ tab,
                                          int off4) {
    float4 c = {0.f, 0.f, 0.f, 0.f};
    int k[8];
    float4 wA[8], wB[8];
    ext8(M, k); load8h(wA, tab, k, off4);
    for (;;) {
        if (!any(M)) { cons8h(c, wA); break; }
        ext8(M, k); load8h(wB, tab, k, off4); cons8h(c, wA);
        if (!any(M)) { cons8h(c, wB); break; }
        ext8(M, k); load8h(wA, tab, k, off4); cons8h(c, wB);
    }
    return c;
}

__device__ __forceinline__ void load8o(float2* w, const float* __restrict__ tab,
                                       const int* k, int off2) {
    #pragma unroll
    for (int i = 0; i < 8; ++i)
        w[i] = *(const float2*)(tab + (size_t)k[i] * 128 + off2);
}

__device__ __forceinline__ void cons8o(float2& c, const float2* w) {
    #pragma unroll
    for (int i = 0; i < 8; ++i) {
        c.x = __fadd_rn(c.x, w[i].x);
        c.y = __fadd_rn(c.y, w[i].y);
    }
}

__device__ __forceinline__ float2 out_sum(Masks M, const float* __restrict__ tab,
                                          int off2) {
    float2 c = {0.f, 0.f};
    int k[8];
    float2 wA[8], wB[8];
    ext8(M, k); load8o(wA, tab, k, off2);
    for (;;) {
        if (!any(M)) { cons8o(c, wA); break; }
        ext8(M, k); load8o(wB, tab, k, off2); cons8o(c, wA);
        if (!any(M)) { cons8o(c, wB); break; }
        ext8(M, k); load8o(wA, tab, k, off2); cons8o(c, wB);
    }
    return c;
}

// ---------------- recurrent kernel: one WAVE per batch row -----------------
// 256 threads = 4 independent waves (no __syncthreads). Lane owns neurons
// 4L..4L+3 (hidden) and outputs 2L, 2L+1 (mf|ma combined).
__global__ __launch_bounds__(256, 1) void snn_rec(
    const float* __restrict__ cur1,     // [b][t_local][h]
    const float* __restrict__ Wt_h, const float* __restrict__ Wt_h1,
    const float* __restrict__ WtO,
    const float* __restrict__ beta1, const float* __restrict__ thr1,
    const float* __restrict__ b_h,  const float* __restrict__ beta2, const float* __restrict__ thr2,
    const float* __restrict__ b_h1,
    const float* __restrict__ b_f,  const float* __restrict__ beta_f,
    const float* __restrict__ b_a,  const float* __restrict__ beta_a,
    float* __restrict__ m1s, float* __restrict__ m2s, float* __restrict__ m3s,
    float* __restrict__ mos, float* __restrict__ out,
    int TC, int first)
{
    const int tid  = threadIdx.x;
    const int lane = tid & 63;
    const int b    = blockIdx.x * 4 + (tid >> 6);
    const int off4 = lane * 4;          // hidden neuron base 4L
    const int off2 = lane * 2;          // output slot base 2L

    // per-lane params (4 contiguous hidden neurons)
    const float4 B1v  = *(const float4*)(beta1 + off4);
    const float4 Th1v = *(const float4*)(thr1  + off4);
    const float4 bhv  = *(const float4*)(b_h   + off4);
    const float4 B2v  = *(const float4*)(beta2 + off4);
    const float4 Th2v = *(const float4*)(thr2  + off4);
    const float4 bh1v = *(const float4*)(b_h1  + off4);
    const float4 B1c  = {clamp01(B1v.x), clamp01(B1v.y), clamp01(B1v.z), clamp01(B1v.w)};
    const float4 B2c  = {clamp01(B2v.x), clamp01(B2v.y), clamp01(B2v.z), clamp01(B2v.w)};

    const int oo = off2 & 63;
    const float* bop = (lane < 32) ? b_f    : b_a;
    const float* Bop = (lane < 32) ? beta_f : beta_a;
    const float bo0 = bop[oo], bo1 = bop[oo + 1];
    const float Bo0 = clamp01(Bop[oo]), Bo1 = clamp01(Bop[oo + 1]);

    float4 m1, m2, m3;
    float mo0, mo1;
    if (first) {
        m1 = m2 = m3 = make_float4(0.f, 0.f, 0.f, 0.f);
        mo0 = mo1 = 0.f;
    } else {
        m1 = *(const float4*)(m1s + (size_t)b * Hh + off4);
        m2 = *(const float4*)(m2s + (size_t)b * Hh + off4);
        m3 = *(const float4*)(m3s + (size_t)b * Hh + off4);
        const float2 mo = *(const float2*)(mos + (size_t)b * 128 + off2);
        mo0 = mo.x; mo1 = mo.y;
    }

    const float* __restrict__ curb = cur1 + (size_t)b * TC * Hh + off4;
    float4 cur = *(const float4*)(curb);

    for (int t = 0; t < TC; ++t) {
        // ---- layer 1 (cur precomputed by GEMM, bias included) -------------
        int nib = 0;
        nib |= (int)lif_step(m1.x, cur.x, B1c.x, Th1v.x);
        nib |= (int)lif_step(m1.y, cur.y, B1c.y, Th1v.y) << 1;
        nib |= (int)lif_step(m1.z, cur.z, B1c.z, Th1v.z) << 2;
        nib |= (int)lif_step(m1.w, cur.w, B1c.w, Th1v.w) << 3;
        Masks M = make_masks(nib, lane);
        if (t + 1 < TC) cur = *(const float4*)(curb + (size_t)(t + 1) * Hh);  // prefetch

        // ---- layer 2 ------------------------------------------------------
        float4 s = hid_sum(M, Wt_h, off4);
        nib  = (int)lif_step(m2.x, __fadd_rn(s.x, bhv.x), B2c.x, Th2v.x);
        nib |= (int)lif_step(m2.y, __fadd_rn(s.y, bhv.y), B2c.y, Th2v.y) << 1;
        nib |= (int)lif_step(m2.z, __fadd_rn(s.z, bhv.z), B2c.z, Th2v.z) << 2;
        nib |= (int)lif_step(m2.w, __fadd_rn(s.w, bhv.w), B2c.w, Th2v.w) << 3;
        M = make_masks(nib, lane);

        // ---- layer 3 (reuses beta2/thr2 — source bug preserved) ----------
        s = hid_sum(M, Wt_h1, off4);
        nib  = (int)lif_step(m3.x, __fadd_rn(s.x, bh1v.x), B2c.x, Th2v.x);
        nib |= (int)lif_step(m3.y, __fadd_rn(s.y, bh1v.y), B2c.y, Th2v.y) << 1;
        nib |= (int)lif_step(m3.z, __fadd_rn(s.z, bh1v.z), B2c.z, Th2v.z) << 2;
        nib |= (int)lif_step(m3.w, __fadd_rn(s.w, bh1v.w), B2c.w, Th2v.w) << 3;
        M = make_masks(nib, lane);

        // ---- output LI neurons (no reset) --------------------------------
        const float2 os = out_sum(M, WtO, off2);
        mo0 = __fadd_rn(__fmul_rn(Bo0, mo0), __fadd_rn(os.x, bo0));
        mo1 = __fadd_rn(__fmul_rn(Bo1, mo1), __fadd_rn(os.y, bo1));
    }

    *(float4*)(m1s + (size_t)b * Hh + off4) = m1;
    *(float4*)(m2s + (size_t)b * Hh + off4) = m2;
    *(float4*)(m3s + (size_t)b * Hh + off4) = m3;
    *(float2*)(mos + (size_t)b * 128 + off2) = make_float2(mo0, mo1);

    float* dst = out + ((lane < 32) ? 0 : (size_t)Bsz * Oo) + (size_t)b * Oo + oo;
    const float o0 = (float)(1.0 / (1.0 + exp(-(double)mo0)));
    const float o1 = (float)(1.0 / (1.0 + exp(-(double)mo1)));
    *(float2*)dst = make_float2(o0, o1);
}

// ---------------- layer-1 GEMM, LDS-tiled (TT columns per block) -----------
template<int TT>
__global__ __launch_bounds__(256) void gemm_l1_lds(
    const float* __restrict__ x, const float* __restrict__ Wt_in,
    const float* __restrict__ b_in, float* __restrict__ cur1,
    int tg_base, int TCloc)
{
    __shared__ float xs[Dd][TT];
    const int h   = threadIdx.x;
    const int b   = blockIdx.x;
    const int ty  = blockIdx.y;
    const int tg0 = tg_base + ty * TT;
    const float* xb = x + (size_t)b * Dd * Tt + tg0;
    constexpr int T4 = TT / 4;
    for (int v = threadIdx.x; v < Dd * T4; v += 256) {
        const int d = v / T4, j4 = v - d * T4;
        *(float4*)&xs[d][j4 * 4] = *(const float4*)(xb + (size_t)d * Tt + j4 * 4);
    }
    __syncthreads();
    float c[TT];
    #pragma unroll
    for (int j = 0; j < TT; ++j) c[j] = 0.f;
    for (int d = 0; d < Dd; ++d) {
        const float w = Wt_in[d * Hh + h];        // coalesced
        #pragma unroll
        for (int j = 0; j < TT; ++j) c[j] = fmaf(w, xs[d][j], c[j]);  // broadcast
    }
    const float bb = b_in[h];
    float* cb = cur1 + ((size_t)b * TCloc + ty * TT) * Hh;
    #pragma unroll
    for (int j = 0; j < TT; ++j) cb[j * Hh + h] = __fadd_rn(c[j], bb);
}

template<int TT>
__global__ __launch_bounds__(256) void gemm_l1_simple(
    const float* __restrict__ x, const float* __restrict__ Wt_in,
    const float* __restrict__ b_in, float* __restrict__ cur1, int tg0)
{
    const int h = threadIdx.x;
    const int b = blockIdx.x;
    float c[TT];
    #pragma unroll
    for (int j = 0; j < TT; ++j) c[j] = 0.f;
    const float* xb = x + (size_t)b * Dd * Tt + tg0;
    for (int d = 0; d < Dd; ++d) {
        const float w = Wt_in[d * Hh + h];
        const float* xp = xb + (size_t)d * Tt;
        #pragma unroll
        for (int j = 0; j < TT; ++j) c[j] = fmaf(w, xp[j], c[j]);
    }
    const float bb = b_in[h];
    float* cb = cur1 + (size_t)b * TT * Hh;
    #pragma unroll
    for (int j = 0; j < TT; ++j) cb[j * Hh + h] = __fadd_rn(c[j], bb);
}

} // namespace

extern "C" void kernel_launch(void* const* d_in, const int* in_sizes, int n_in,
                              void* d_out, int out_size, void* d_ws, size_t ws_size,
                              hipStream_t stream) {
    const float* x      = (const float*)d_in[0];
    const float* W_in   = (const float*)d_in[1];
    const float* b_in   = (const float*)d_in[2];
    const float* beta1  = (const float*)d_in[3];
    const float* thr1   = (const float*)d_in[4];
    const float* W_h    = (const float*)d_in[5];
    const float* b_h    = (const float*)d_in[6];
    const float* beta2  = (const float*)d_in[7];
    const float* thr2   = (const float*)d_in[8];
    const float* W_h1   = (const float*)d_in[9];
    const float* b_h1   = (const float*)d_in[10];
    const float* W_f    = (const float*)d_in[11];
    const float* b_f    = (const float*)d_in[12];
    const float* beta_f = (const float*)d_in[13];
    const float* W_a    = (const float*)d_in[14];
    const float* b_a    = (const float*)d_in[15];
    const float* beta_a = (const float*)d_in[16];
    float* out = (float*)d_out;

    float* ws = (float*)d_ws;
    size_t off = 0;
    auto alloc = [&](size_t n) { float* p = ws + off; off += n; return p; };
    float* Wt_in = alloc(257 * 256);
    float* Wt_h  = alloc(257 * 256);
    float* Wt_h1 = alloc(257 * 256);
    float* WtO   = alloc(257 * 128);
    float* m1s   = alloc((size_t)Bsz * Hh);
    float* m2s   = alloc((size_t)Bsz * Hh);
    float* m3s   = alloc((size_t)Bsz * Hh);
    float* mos   = alloc((size_t)Bsz * 128);
    const size_t fixed = off;

    int TC = 1;
    const int cands[8] = {128, 64, 32, 16, 8, 4, 2, 1};
    for (int i = 0; i < 8; ++i) {
        if ((fixed + (size_t)cands[i] * Bsz * Hh) * sizeof(float) <= ws_size) { TC = cands[i]; break; }
    }
    float* cur1 = alloc((size_t)TC * Bsz * Hh);

    pack_t<<<257, 256, 0, stream>>>(W_in, Wt_in, 256, 256);
    pack_t<<<257, 256, 0, stream>>>(W_h,  Wt_h,  256, 256);
    pack_t<<<257, 256, 0, stream>>>(W_h1, Wt_h1, 256, 256);
    pack_o<<<129, 256, 0, stream>>>(W_f, W_a, WtO);

    const int nch = Tt / TC;
    for (int c = 0; c < nch; ++c) {
        const int tg = c * TC;
        if (TC >= 32)
            gemm_l1_lds<32><<<dim3(Bsz, TC / 32), 256, 0, stream>>>(x, Wt_in, b_in, cur1, tg, TC);
        else if (TC == 16)
            gemm_l1_lds<16><<<dim3(Bsz, 1), 256, 0, stream>>>(x, Wt_in, b_in, cur1, tg, TC);
        else if (TC == 8)
            gemm_l1_lds<8><<<dim3(Bsz, 1), 256, 0, stream>>>(x, Wt_in, b_in, cur1, tg, TC);
        else if (TC == 4)
            gemm_l1_simple<4><<<Bsz, 256, 0, stream>>>(x, Wt_in, b_in, cur1, tg);
        else if (TC == 2)
            gemm_l1_simple<2><<<Bsz, 256, 0, stream>>>(x, Wt_in, b_in, cur1, tg);
        else
            gemm_l1_simple<1><<<Bsz, 256, 0, stream>>>(x, Wt_in, b_in, cur1, tg);

        snn_rec<<<Bsz / 4, 256, 0, stream>>>(
            cur1, Wt_h, Wt_h1, WtO,
            beta1, thr1, b_h, beta2, thr2, b_h1,
            b_f, beta_f, b_a, beta_a,
            m1s, m2s, m3s, mos, out, TC, (c == 0) ? 1 : 0);
    }
}

// Round 7
// 1349.836 us; speedup vs baseline: 1.6471x; 1.4442x over previous
//
#include <hip/hip_runtime.h>
#include <math.h>
#include <stdint.h>

// ---------------------------------------------------------------------------
// SNN forward — R7: wave-per-row + branchless rank compaction + counted
// depth-2 pipelined gathers.
//
// Bit-exactness contract (R3..R6, absmax 4.882812e-4):
//   - layer-1: c=0; for d ascending: c=fmaf(w,x,c); then __fadd_rn(c,bias)
//   - spike layers: sum over spiking k ASCENDING, sequential __fadd_rn chain
//     seeded 0; sentinel k=256 hits zeroed row (c+0=c; c never -0)
//   - LIF: individually-rounded fp32 ops, reset from PREVIOUS mem
//
// R6 post-mortem: VALUBusy 8.7% — branchy scalar ctz walk (32 s_cbranch per
// batch) + dynamic loop defeated load pipelining. R7: lanes compute global
// spike ranks arithmetically (no branches), write u16 lists to per-wave LDS,
// consume with counted uniform loops, manual depth-2 (16 loads in flight).
// No __syncthreads anywhere in the recurrence (per-wave lists).
// ---------------------------------------------------------------------------

namespace {

constexpr int Bsz = 1024;
constexpr int Dd  = 256;
constexpr int Tt  = 128;
constexpr int Hh  = 256;
constexpr int Oo  = 64;

// Wt[c*R + r] = W[r*C + c] for c<C; row c==C zeroed (sparse sentinel target).
__global__ void pack_t(const float* __restrict__ W, float* __restrict__ Wt,
                       int R, int C) {
    int idx = blockIdx.x * 256 + threadIdx.x;
    if (idx >= (C + 1) * R) return;
    int c = idx / R, r = idx - c * R;
    Wt[idx] = (c < C) ? W[(size_t)r * C + c] : 0.f;
}

// WtO[k*128 + o]: o<64 -> W_f[o][k], o>=64 -> W_a[o-64][k]; row k==256 zeroed.
__global__ void pack_o(const float* __restrict__ Wf, const float* __restrict__ Wa,
                       float* __restrict__ WtO) {
    int idx = blockIdx.x * 256 + threadIdx.x;
    if (idx >= 257 * 128) return;
    int k = idx >> 7, o = idx & 127;
    float v = 0.f;
    if (k < 256) v = (o < 64) ? Wf[(size_t)o * 256 + k] : Wa[(size_t)(o - 64) * 256 + k];
    WtO[idx] = v;
}

__device__ __forceinline__ float clamp01(float v) { return fminf(fmaxf(v, 0.f), 1.f); }

__device__ __forceinline__ bool lif_step(float& m, float cur, float B, float Th) {
    const float r = (__fsub_rn(m, Th) > 0.f) ? Th : 0.f;   // reset from PREVIOUS mem
    m = __fsub_rn(__fadd_rn(__fmul_rn(B, m), cur), r);
    return __fsub_rn(m, Th) > 0.f;
}

// Build 256-bit spike mask from 4 bits/lane (lane owns neurons 4L..4L+3):
// word q bit p = neuron 64q+p, contributed by lane 16q+(p>>2), bit (p&3).
__device__ __forceinline__ void make_masks(int nib, int lane, uint64_t* M) {
    #pragma unroll
    for (int q = 0; q < 4; ++q) {
        const int v   = __shfl(nib, 16 * q + (lane >> 2), 64);
        const int bit = (v >> (lane & 3)) & 1;
        M[q] = __ballot(bit != 0);
    }
}

// Branchless compaction: write ascending-neuron u16 index list to lst,
// pad to multiple of 8 with sentinel Hh. Returns npad (uniform).
__device__ __forceinline__ int compact(int nib, int lane, const uint64_t* M,
                                       uint16_t* lst) {
    const int p0 = (int)__popcll(M[0]);
    const int p1 = (int)__popcll(M[1]);
    const int p2 = (int)__popcll(M[2]);
    const int p3 = (int)__popcll(M[3]);
    const int q  = lane >> 4;
    const int base = ((q >= 1) ? p0 : 0) + ((q >= 2) ? p1 : 0) + ((q >= 3) ? p2 : 0);
    const uint64_t mq = (q & 2) ? ((q & 1) ? M[3] : M[2])
                                : ((q & 1) ? M[1] : M[0]);
    const int posb = (lane & 15) << 2;
    const int r0 = base + (int)__popcll(mq & ((1ull << posb) - 1ull));
    const int s1 = nib & 1;
    const int s2 = s1 + ((nib >> 1) & 1);
    const int s3 = s2 + ((nib >> 2) & 1);
    const int nb = lane << 2;
    if (nib & 1) lst[r0]      = (uint16_t)nb;
    if (nib & 2) lst[r0 + s1] = (uint16_t)(nb + 1);
    if (nib & 4) lst[r0 + s2] = (uint16_t)(nb + 2);
    if (nib & 8) lst[r0 + s3] = (uint16_t)(nb + 3);
    const int n    = p0 + p1 + p2 + p3;
    const int npad = (n + 7) & ~7;
    if (lane < npad - n) lst[n + lane] = (uint16_t)Hh;
    return npad;
}

// ---- hidden-layer gather: 8 dwordx4 loads per batch, depth-2 pipeline -----

__device__ __forceinline__ void issue8h(const char* __restrict__ tab,
                                        uint4 I, int offB, float4* w) {
    const int k[8] = {(int)(I.x & 0xffff), (int)(I.x >> 16),
                      (int)(I.y & 0xffff), (int)(I.y >> 16),
                      (int)(I.z & 0xffff), (int)(I.z >> 16),
                      (int)(I.w & 0xffff), (int)(I.w >> 16)};
    #pragma unroll
    for (int i = 0; i < 8; ++i)
        w[i] = *(const float4*)(tab + (k[i] << 10) + offB);
}

__device__ __forceinline__ void cons8h(float4& c, const float4* w) {
    #pragma unroll
    for (int i = 0; i < 8; ++i) {
        c.x = __fadd_rn(c.x, w[i].x);
        c.y = __fadd_rn(c.y, w[i].y);
        c.z = __fadd_rn(c.z, w[i].z);
        c.w = __fadd_rn(c.w, w[i].w);
    }
}

__device__ __forceinline__ float4 sum_h(const uint16_t* lst, int nbat,
                                        const float* __restrict__ tab, int offB) {
    float4 c = {0.f, 0.f, 0.f, 0.f};
    if (nbat == 0) return c;
    const char* tb = (const char*)tab;
    float4 A[8], B[8];
    issue8h(tb, *(const uint4*)(lst), offB, A);
    int i = 1;
    for (; i + 1 < nbat; i += 2) {
        issue8h(tb, *(const uint4*)(lst + 8 * i), offB, B);
        cons8h(c, A);
        issue8h(tb, *(const uint4*)(lst + 8 * (i + 1)), offB, A);
        cons8h(c, B);
    }
    if (i < nbat) {
        issue8h(tb, *(const uint4*)(lst + 8 * i), offB, B);
        cons8h(c, A);
        cons8h(c, B);
    } else {
        cons8h(c, A);
    }
    return c;
}

// ---- output-layer gather: 8 dwordx2 loads per batch, depth-2 pipeline -----

__device__ __forceinline__ void issue8o(const char* __restrict__ tab,
                                        uint4 I, int offB, float2* w) {
    const int k[8] = {(int)(I.x & 0xffff), (int)(I.x >> 16),
                      (int)(I.y & 0xffff), (int)(I.y >> 16),
                      (int)(I.z & 0xffff), (int)(I.z >> 16),
                      (int)(I.w & 0xffff), (int)(I.w >> 16)};
    #pragma unroll
    for (int i = 0; i < 8; ++i)
        w[i] = *(const float2*)(tab + (k[i] << 9) + offB);
}

__device__ __forceinline__ void cons8o(float2& c, const float2* w) {
    #pragma unroll
    for (int i = 0; i < 8; ++i) {
        c.x = __fadd_rn(c.x, w[i].x);
        c.y = __fadd_rn(c.y, w[i].y);
    }
}

__device__ __forceinline__ float2 sum_o(const uint16_t* lst, int nbat,
                                        const float* __restrict__ tab, int offB) {
    float2 c = {0.f, 0.f};
    if (nbat == 0) return c;
    const char* tb = (const char*)tab;
    float2 A[8], B[8];
    issue8o(tb, *(const uint4*)(lst), offB, A);
    int i = 1;
    for (; i + 1 < nbat; i += 2) {
        issue8o(tb, *(const uint4*)(lst + 8 * i), offB, B);
        cons8o(c, A);
        issue8o(tb, *(const uint4*)(lst + 8 * (i + 1)), offB, A);
        cons8o(c, B);
    }
    if (i < nbat) {
        issue8o(tb, *(const uint4*)(lst + 8 * i), offB, B);
        cons8o(c, A);
        cons8o(c, B);
    } else {
        cons8o(c, A);
    }
    return c;
}

// ---------------- recurrent kernel: one WAVE per batch row -----------------
// 256 threads = 4 independent waves, per-wave LDS lists, no __syncthreads.
// Lane owns neurons 4L..4L+3 (hidden) and outputs 2L, 2L+1 (mf|ma combined).
__global__ __launch_bounds__(256, 1) void snn_rec(
    const float* __restrict__ cur1,     // [b][t_local][h]
    const float* __restrict__ Wt_h, const float* __restrict__ Wt_h1,
    const float* __restrict__ WtO,
    const float* __restrict__ beta1, const float* __restrict__ thr1,
    const float* __restrict__ b_h,  const float* __restrict__ beta2, const float* __restrict__ thr2,
    const float* __restrict__ b_h1,
    const float* __restrict__ b_f,  const float* __restrict__ beta_f,
    const float* __restrict__ b_a,  const float* __restrict__ beta_a,
    float* __restrict__ m1s, float* __restrict__ m2s, float* __restrict__ m3s,
    float* __restrict__ mos, float* __restrict__ out,
    int TC, int first)
{
    __shared__ __attribute__((aligned(16))) uint16_t lists[4][272];

    const int tid  = threadIdx.x;
    const int lane = tid & 63;
    const int b    = blockIdx.x * 4 + (tid >> 6);
    uint16_t* lst  = lists[tid >> 6];
    const int off4 = lane * 4;          // hidden neuron base 4L
    const int off2 = lane * 2;          // output slot base 2L
    const int offBh = lane * 16;        // byte offset into 1KB hidden rows
    const int offBo = lane * 8;         // byte offset into 512B output rows

    const float4 B1v  = *(const float4*)(beta1 + off4);
    const float4 Th1v = *(const float4*)(thr1  + off4);
    const float4 bhv  = *(const float4*)(b_h   + off4);
    const float4 B2v  = *(const float4*)(beta2 + off4);
    const float4 Th2v = *(const float4*)(thr2  + off4);
    const float4 bh1v = *(const float4*)(b_h1  + off4);
    const float4 B1c  = {clamp01(B1v.x), clamp01(B1v.y), clamp01(B1v.z), clamp01(B1v.w)};
    const float4 B2c  = {clamp01(B2v.x), clamp01(B2v.y), clamp01(B2v.z), clamp01(B2v.w)};

    const int oo = off2 & 63;
    const float* bop = (lane < 32) ? b_f    : b_a;
    const float* Bop = (lane < 32) ? beta_f : beta_a;
    const float bo0 = bop[oo], bo1 = bop[oo + 1];
    const float Bo0 = clamp01(Bop[oo]), Bo1 = clamp01(Bop[oo + 1]);

    float4 m1, m2, m3;
    float mo0, mo1;
    if (first) {
        m1 = m2 = m3 = make_float4(0.f, 0.f, 0.f, 0.f);
        mo0 = mo1 = 0.f;
    } else {
        m1 = *(const float4*)(m1s + (size_t)b * Hh + off4);
        m2 = *(const float4*)(m2s + (size_t)b * Hh + off4);
        m3 = *(const float4*)(m3s + (size_t)b * Hh + off4);
        const float2 mo = *(const float2*)(mos + (size_t)b * 128 + off2);
        mo0 = mo.x; mo1 = mo.y;
    }

    const float* __restrict__ curb = cur1 + (size_t)b * TC * Hh + off4;
    float4 cur = *(const float4*)(curb);
    uint64_t M[4];

    for (int t = 0; t < TC; ++t) {
        // ---- layer 1 (cur precomputed by GEMM, bias included) -------------
        int nib = 0;
        nib |= (int)lif_step(m1.x, cur.x, B1c.x, Th1v.x);
        nib |= (int)lif_step(m1.y, cur.y, B1c.y, Th1v.y) << 1;
        nib |= (int)lif_step(m1.z, cur.z, B1c.z, Th1v.z) << 2;
        nib |= (int)lif_step(m1.w, cur.w, B1c.w, Th1v.w) << 3;
        make_masks(nib, lane, M);
        int npad = compact(nib, lane, M, lst);
        if (t + 1 < TC) cur = *(const float4*)(curb + (size_t)(t + 1) * Hh);  // prefetch

        // ---- layer 2 ------------------------------------------------------
        float4 s = sum_h(lst, npad >> 3, Wt_h, offBh);
        nib  = (int)lif_step(m2.x, __fadd_rn(s.x, bhv.x), B2c.x, Th2v.x);
        nib |= (int)lif_step(m2.y, __fadd_rn(s.y, bhv.y), B2c.y, Th2v.y) << 1;
        nib |= (int)lif_step(m2.z, __fadd_rn(s.z, bhv.z), B2c.z, Th2v.z) << 2;
        nib |= (int)lif_step(m2.w, __fadd_rn(s.w, bhv.w), B2c.w, Th2v.w) << 3;
        make_masks(nib, lane, M);
        npad = compact(nib, lane, M, lst);

        // ---- layer 3 (reuses beta2/thr2 — source bug preserved) ----------
        s = sum_h(lst, npad >> 3, Wt_h1, offBh);
        nib  = (int)lif_step(m3.x, __fadd_rn(s.x, bh1v.x), B2c.x, Th2v.x);
        nib |= (int)lif_step(m3.y, __fadd_rn(s.y, bh1v.y), B2c.y, Th2v.y) << 1;
        nib |= (int)lif_step(m3.z, __fadd_rn(s.z, bh1v.z), B2c.z, Th2v.z) << 2;
        nib |= (int)lif_step(m3.w, __fadd_rn(s.w, bh1v.w), B2c.w, Th2v.w) << 3;
        make_masks(nib, lane, M);
        npad = compact(nib, lane, M, lst);

        // ---- output LI neurons (no reset) --------------------------------
        const float2 os = sum_o(lst, npad >> 3, WtO, offBo);
        mo0 = __fadd_rn(__fmul_rn(Bo0, mo0), __fadd_rn(os.x, bo0));
        mo1 = __fadd_rn(__fmul_rn(Bo1, mo1), __fadd_rn(os.y, bo1));
    }

    *(float4*)(m1s + (size_t)b * Hh + off4) = m1;
    *(float4*)(m2s + (size_t)b * Hh + off4) = m2;
    *(float4*)(m3s + (size_t)b * Hh + off4) = m3;
    *(float2*)(mos + (size_t)b * 128 + off2) = make_float2(mo0, mo1);

    float* dst = out + ((lane < 32) ? 0 : (size_t)Bsz * Oo) + (size_t)b * Oo + oo;
    const float o0 = (float)(1.0 / (1.0 + exp(-(double)mo0)));
    const float o1 = (float)(1.0 / (1.0 + exp(-(double)mo1)));
    *(float2*)dst = make_float2(o0, o1);
}

// ---------------- layer-1 GEMM, LDS-tiled (TT columns per block) -----------
template<int TT>
__global__ __launch_bounds__(256) void gemm_l1_lds(
    const float* __restrict__ x, const float* __restrict__ Wt_in,
    const float* __restrict__ b_in, float* __restrict__ cur1,
    int tg_base, int TCloc)
{
    __shared__ float xs[Dd][TT];
    const int h   = threadIdx.x;
    const int b   = blockIdx.x;
    const int ty  = blockIdx.y;
    const int tg0 = tg_base + ty * TT;
    const float* xb = x + (size_t)b * Dd * Tt + tg0;
    constexpr int T4 = TT / 4;
    for (int v = threadIdx.x; v < Dd * T4; v += 256) {
        const int d = v / T4, j4 = v - d * T4;
        *(float4*)&xs[d][j4 * 4] = *(const float4*)(xb + (size_t)d * Tt + j4 * 4);
    }
    __syncthreads();
    float c[TT];
    #pragma unroll
    for (int j = 0; j < TT; ++j) c[j] = 0.f;
    for (int d = 0; d < Dd; ++d) {
        const float w = Wt_in[d * Hh + h];        // coalesced
        #pragma unroll
        for (int j = 0; j < TT; ++j) c[j] = fmaf(w, xs[d][j], c[j]);  // broadcast
    }
    const float bb = b_in[h];
    float* cb = cur1 + ((size_t)b * TCloc + ty * TT) * Hh;
    #pragma unroll
    for (int j = 0; j < TT; ++j) cb[j * Hh + h] = __fadd_rn(c[j], bb);
}

template<int TT>
__global__ __launch_bounds__(256) void gemm_l1_simple(
    const float* __restrict__ x, const float* __restrict__ Wt_in,
    const float* __restrict__ b_in, float* __restrict__ cur1, int tg0)
{
    const int h = threadIdx.x;
    const int b = blockIdx.x;
    float c[TT];
    #pragma unroll
    for (int j = 0; j < TT; ++j) c[j] = 0.f;
    const float* xb = x + (size_t)b * Dd * Tt + tg0;
    for (int d = 0; d < Dd; ++d) {
        const float w = Wt_in[d * Hh + h];
        const float* xp = xb + (size_t)d * Tt;
        #pragma unroll
        for (int j = 0; j < TT; ++j) c[j] = fmaf(w, xp[j], c[j]);
    }
    const float bb = b_in[h];
    float* cb = cur1 + (size_t)b * TT * Hh;
    #pragma unroll
    for (int j = 0; j < TT; ++j) cb[j * Hh + h] = __fadd_rn(c[j], bb);
}

} // namespace

extern "C" void kernel_launch(void* const* d_in, const int* in_sizes, int n_in,
                              void* d_out, int out_size, void* d_ws, size_t ws_size,
                              hipStream_t stream) {
    const float* x      = (const float*)d_in[0];
    const float* W_in   = (const float*)d_in[1];
    const float* b_in   = (const float*)d_in[2];
    const float* beta1  = (const float*)d_in[3];
    const float* thr1   = (const float*)d_in[4];
    const float* W_h    = (const float*)d_in[5];
    const float* b_h    = (const float*)d_in[6];
    const float* beta2  = (const float*)d_in[7];
    const float* thr2   = (const float*)d_in[8];
    const float* W_h1   = (const float*)d_in[9];
    const float* b_h1   = (const float*)d_in[10];
    const float* W_f    = (const float*)d_in[11];
    const float* b_f    = (const float*)d_in[12];
    const float* beta_f = (const float*)d_in[13];
    const float* W_a    = (const float*)d_in[14];
    const float* b_a    = (const float*)d_in[15];
    const float* beta_a = (const float*)d_in[16];
    float* out = (float*)d_out;

    float* ws = (float*)d_ws;
    size_t off = 0;
    auto alloc = [&](size_t n) { float* p = ws + off; off += n; return p; };
    float* Wt_in = alloc(257 * 256);
    float* Wt_h  = alloc(257 * 256);
    float* Wt_h1 = alloc(257 * 256);
    float* WtO   = alloc(257 * 128);
    float* m1s   = alloc((size_t)Bsz * Hh);
    float* m2s   = alloc((size_t)Bsz * Hh);
    float* m3s   = alloc((size_t)Bsz * Hh);
    float* mos   = alloc((size_t)Bsz * 128);
    const size_t fixed = off;

    int TC = 1;
    const int cands[8] = {128, 64, 32, 16, 8, 4, 2, 1};
    for (int i = 0; i < 8; ++i) {
        if ((fixed + (size_t)cands[i] * Bsz * Hh) * sizeof(float) <= ws_size) { TC = cands[i]; break; }
    }
    float* cur1 = alloc((size_t)TC * Bsz * Hh);

    pack_t<<<257, 256, 0, stream>>>(W_in, Wt_in, 256, 256);
    pack_t<<<257, 256, 0, stream>>>(W_h,  Wt_h,  256, 256);
    pack_t<<<257, 256, 0, stream>>>(W_h1, Wt_h1, 256, 256);
    pack_o<<<129, 256, 0, stream>>>(W_f, W_a, WtO);

    const int nch = Tt / TC;
    for (int c = 0; c < nch; ++c) {
        const int tg = c * TC;
        if (TC >= 32)
            gemm_l1_lds<32><<<dim3(Bsz, TC / 32), 256, 0, stream>>>(x, Wt_in, b_in, cur1, tg, TC);
        else if (TC == 16)
            gemm_l1_lds<16><<<dim3(Bsz, 1), 256, 0, stream>>>(x, Wt_in, b_in, cur1, tg, TC);
        else if (TC == 8)
            gemm_l1_lds<8><<<dim3(Bsz, 1), 256, 0, stream>>>(x, Wt_in, b_in, cur1, tg, TC);
        else if (TC == 4)
            gemm_l1_simple<4><<<Bsz, 256, 0, stream>>>(x, Wt_in, b_in, cur1, tg);
        else if (TC == 2)
            gemm_l1_simple<2><<<Bsz, 256, 0, stream>>>(x, Wt_in, b_in, cur1, tg);
        else
            gemm_l1_simple<1><<<Bsz, 256, 0, stream>>>(x, Wt_in, b_in, cur1, tg);

        snn_rec<<<Bsz / 4, 256, 0, stream>>>(
            cur1, Wt_h, Wt_h1, WtO,
            beta1, thr1, b_h, beta2, thr2, b_h1,
            b_f, beta_f, b_a, beta_a,
            m1s, m2s, m3s, mos, out, TC, (c == 0) ? 1 : 0);
    }
}